// Round 4
// baseline (152.398 us; speedup 1.0000x reference)
//
#include <hip/hip_runtime.h>
#include <hip/hip_bf16.h>
#include <stdint.h>

// GRU cell, B=32768, IN=256, H=256, CONCAT=512. Fused bf16-MFMA kernel.
// R10 = occupancy restructure. R9 post-mortem: slab pipeline neutral because
// the kernel runs 1 block/CU (220 total regs/lane = 124 arch + 96 acc ->
// 2 waves/SIMD); every latency is exposed and intra-block pipelining can't
// fix that. This version: MT=32 rows/block (grid 1024), acc halves to 48
// regs (rz[4][2] + gac[2][2]), B single-buffered (24 regs), monolithic
// stage, no hand-pinned fences. Pinned budget ~86 + misc ~= 110 total
// -> 4 waves/SIMD, 2 independent blocks/CU (LDS 32 KB x 2 = 64 <= 160).
// Latency hiding via TLP instead of intra-block scheduling. Cost: weight
// L2 traffic doubles (1024 x 768 KB = 786 MB ~= 23 us floor, overlappable).
// __launch_bounds__(512,4) enforces the 128-reg target (feasible now;
// R8's spill came from forcing an infeasible 220->128).

typedef float  f32x4  __attribute__((ext_vector_type(4)));
typedef __bf16 bf16x8 __attribute__((ext_vector_type(8)));
typedef short  s16x8  __attribute__((ext_vector_type(8)));

#define B_TOT   32768
#define MT      32
#define WRZ_ELEMS (512*512)

__device__ __forceinline__ unsigned short f2b(float f) {
    union { float f; unsigned int u; } v; v.f = f;
    unsigned int r = (v.u + 0x7FFFu + ((v.u >> 16) & 1u)) >> 16;  // RNE
    return (unsigned short)r;
}
__device__ __forceinline__ float b2f(unsigned short b) {
    union { unsigned int u; float f; } v; v.u = ((unsigned int)b) << 16;
    return v.f;
}
__device__ __forceinline__ ushort2 pk2(float a, float b) {   // v_cvt_pk_bf16_f32
    __hip_bfloat162 t = __float22bfloat162_rn(make_float2(a, b));
    union { __hip_bfloat162 h; ushort2 u; } c; c.h = t; return c.u;
}
__device__ __forceinline__ float sigmoid_f(float x) {
    return 1.0f / (1.0f + __expf(-x));
}
__device__ __forceinline__ float tanh_f(float x) {
    return 1.0f - 2.0f / (__expf(2.0f * x) + 1.0f);
}

// bf16 LDS tile 32x512 (32 KB), XOR-swizzled at 16B (8-elem) granularity.
__device__ __forceinline__ int lds_idx(int row, int col) {
    return row * 512 + ((((col >> 3) ^ (row & 7)) << 3) | (col & 7));
}

// ---------------------------------------------------------------------------
// Prep (unchanged): fp32 -> bf16 ks-major per-wave fragment pages.
// wrz page (wave w): [ks 0..15][jn 0..3][512]; jn 0,1 r-cols, jn 2,3 z-cols.
// wg  page (wave w): [ks 0..15][j 0..1][512]; k<256 whx, k>=256 whh.
// ---------------------------------------------------------------------------
__global__ void prep_weights(const float* __restrict__ wr,
                             const float* __restrict__ wz,
                             const float* __restrict__ whh,
                             const float* __restrict__ whx,
                             unsigned short* __restrict__ wrz,
                             unsigned short* __restrict__ wg) {
    const int b = blockIdx.x;
    const int t = threadIdx.x;
    union { s16x8 v; unsigned short u[8]; } tmp;

    if (b < 128) {                       // wrz: block = (w, ks)
        int w = b >> 4, ks = b & 15;
        int jn = t >> 6, l = t & 63;
        int kbase = ks * 32 + ((l >> 4) << 3);
        int n = 32 * w + ((jn & 1) << 4) + (l & 15);
        const float* src = (jn < 2) ? wr : wz;
        #pragma unroll
        for (int jj = 0; jj < 8; ++jj)
            tmp.u[jj] = f2b(src[(kbase + jj) * 256 + n]);
        *reinterpret_cast<s16x8*>(wrz + (size_t)w * 32768 + ks * 2048 + t * 8) = tmp.v;
    } else {                             // wg: block = (w, ks-pair)
        int b2 = b - 128;
        int w = b2 >> 3, ksp = b2 & 7;
        int ksl = t >> 7, j = (t >> 6) & 1, l = t & 63;
        int ks = ksp * 2 + ksl;
        int kbase = ks * 32 + ((l >> 4) << 3);
        int n = 32 * w + (j << 4) + (l & 15);
        #pragma unroll
        for (int jj = 0; jj < 8; ++jj) {
            int k = kbase + jj;
            tmp.u[jj] = f2b((k < 256) ? whx[k * 256 + n] : whh[(k - 256) * 256 + n]);
        }
        *reinterpret_cast<s16x8*>(wg + (size_t)w * 16384 + ksp * 2048 + t * 8) = tmp.v;
    }
}

// ---------------------------------------------------------------------------
// Fused GRU: 512 threads (8 waves), 32 rows/block, grid 1024.
// Wave w owns r/z/g cols [32w,32w+32). Monolithic stage, straight K-loop
// with single-buffered B-frags; latency hidden by 2 blocks/CU TLP.
// Gates: a=sigmoid(r+br)*h -> x-region; h stashed in r-acc.
// Tail: g += a @ whh (kt 0..7). Epilogue: h + z*(tanh(g+bh)-h).
// ---------------------------------------------------------------------------
__global__ __launch_bounds__(512, 4)
void gru_fused(const float* __restrict__ x, const float* __restrict__ h,
               const unsigned short* __restrict__ wrz,
               const unsigned short* __restrict__ wg,
               const float* __restrict__ br, const float* __restrict__ bz,
               const float* __restrict__ bh, float* __restrict__ out) {
    __shared__ unsigned short xcA[32 * 512];   // 32 KB

    const int tid  = threadIdx.x;
    const int lane = tid & 63;
    const int wv   = tid >> 6;          // wave 0..7
    const int m0   = lane & 15;
    const int q    = lane >> 4;
    const int rowBase = blockIdx.x * MT;

    float brv[2], bzv[2], bhv[2];
    #pragma unroll
    for (int j = 0; j < 2; ++j) {
        int col = 32 * wv + j * 16 + m0;
        brv[j] = br[col]; bzv[j] = bz[col]; bhv[j] = bh[col];
    }

    // ---- Stage [x | h] -> LDS bf16. Thread t: row t>>4, float cols
    // 4*(t&15) + 64u, u=0..3. Lane-consecutive float4 loads (coalesced);
    // 8-B LDS writes land inside one 16-B swizzle block (col&7 in {0,4}).
    {
        const int srow = tid >> 4;
        const int c4   = (tid & 15) << 2;
        const float* xr = x + (size_t)(rowBase + srow) * 256 + c4;
        const float* hr = h + (size_t)(rowBase + srow) * 256 + c4;
        #pragma unroll
        for (int u = 0; u < 4; ++u) {
            float4 xv = *reinterpret_cast<const float4*>(xr + u * 64);
            float4 hv = *reinterpret_cast<const float4*>(hr + u * 64);
            ushort2 x0 = pk2(xv.x, xv.y), x1 = pk2(xv.z, xv.w);
            ushort2 h0 = pk2(hv.x, hv.y), h1 = pk2(hv.z, hv.w);
            ushort4 xb = make_ushort4(x0.x, x0.y, x1.x, x1.y);
            ushort4 hb = make_ushort4(h0.x, h0.y, h1.x, h1.y);
            *reinterpret_cast<ushort4*>(&xcA[lds_idx(srow, u * 64 + c4)])       = xb;
            *reinterpret_cast<ushort4*>(&xcA[lds_idx(srow, 256 + u * 64 + c4)]) = hb;
        }
    }

    const unsigned short* wrzP = wrz + (size_t)wv * 32768;
    const unsigned short* wgP  = wg  + (size_t)wv * 16384;

    __syncthreads();

    f32x4 rz[4][2];     // jn 0,1 = r; jn 2,3 = z
    f32x4 gac[2][2];
    #pragma unroll
    for (int jn = 0; jn < 4; ++jn)
        #pragma unroll
        for (int mt = 0; mt < 2; ++mt)
            rz[jn][mt] = (f32x4){0.f, 0.f, 0.f, 0.f};
    #pragma unroll
    for (int j = 0; j < 2; ++j)
        #pragma unroll
        for (int mt = 0; mt < 2; ++mt)
            gac[j][mt] = (f32x4){0.f, 0.f, 0.f, 0.f};

    // ---- Main K-loop: 16 ks steps. rz over all ks; g(x-part) for ks<8.
    #pragma unroll
    for (int ks = 0; ks < 16; ++ks) {
        s16x8 Bf[4], Bg[2];
        #pragma unroll
        for (int jn = 0; jn < 4; ++jn)
            Bf[jn] = *reinterpret_cast<const s16x8*>(
                wrzP + ks * 2048 + jn * 512 + lane * 8);
        if (ks < 8) {
            #pragma unroll
            for (int j = 0; j < 2; ++j)
                Bg[j] = *reinterpret_cast<const s16x8*>(
                    wgP + ks * 1024 + j * 512 + lane * 8);
        }
        bf16x8 afr[2];
        #pragma unroll
        for (int mt = 0; mt < 2; ++mt) {
            int row = mt * 16 + m0;
            int idx = row * 512 + ((((ks << 2) | q) ^ (row & 7)) << 3);
            afr[mt] = __builtin_bit_cast(bf16x8,
                *reinterpret_cast<const s16x8*>(&xcA[idx]));
        }
        #pragma unroll
        for (int jn = 0; jn < 4; ++jn) {
            bf16x8 bf = __builtin_bit_cast(bf16x8, Bf[jn]);
            #pragma unroll
            for (int mt = 0; mt < 2; ++mt)
                rz[jn][mt] = __builtin_amdgcn_mfma_f32_16x16x32_bf16(
                    afr[mt], bf, rz[jn][mt], 0, 0, 0);
        }
        if (ks < 8) {
            #pragma unroll
            for (int j = 0; j < 2; ++j) {
                bf16x8 bf = __builtin_bit_cast(bf16x8, Bg[j]);
                #pragma unroll
                for (int mt = 0; mt < 2; ++mt)
                    gac[j][mt] = __builtin_amdgcn_mfma_f32_16x16x32_bf16(
                        afr[mt], bf, gac[j][mt], 0, 0, 0);
            }
        }
    }
    __syncthreads();   // all LDS A-reads done before x-region overwrite

    // ---- Gates: a = sigmoid(r+br)*h -> LDS x-region; stash h in r-acc
    #pragma unroll
    for (int j = 0; j < 2; ++j) {
        int col = 32 * wv + j * 16 + m0;
        #pragma unroll
        for (int mt = 0; mt < 2; ++mt) {
            #pragma unroll
            for (int rg = 0; rg < 4; ++rg) {
                int row = mt * 16 + q * 4 + rg;
                float hval = b2f(xcA[lds_idx(row, 256 + col)]);
                float rs = sigmoid_f(rz[j][mt][rg] + brv[j]);
                xcA[lds_idx(row, col)] = f2b(rs * hval);
                rz[j][mt][rg] = hval;
            }
        }
    }
    __syncthreads();   // a visible to all waves

    // ---- Tail: g += a @ whh, kt 0..7 (wg pages 8..15)
    #pragma unroll
    for (int kt = 0; kt < 8; ++kt) {
        s16x8 Tb[2];
        #pragma unroll
        for (int j = 0; j < 2; ++j)
            Tb[j] = *reinterpret_cast<const s16x8*>(
                wgP + (8 + kt) * 1024 + j * 512 + lane * 8);
        bf16x8 afr[2];
        #pragma unroll
        for (int mt = 0; mt < 2; ++mt) {
            int row = mt * 16 + m0;
            int idx = row * 512 + ((((kt << 2) | q) ^ (row & 7)) << 3);
            afr[mt] = __builtin_bit_cast(bf16x8,
                *reinterpret_cast<const s16x8*>(&xcA[idx]));
        }
        #pragma unroll
        for (int j = 0; j < 2; ++j) {
            bf16x8 bf = __builtin_bit_cast(bf16x8, Tb[j]);
            #pragma unroll
            for (int mt = 0; mt < 2; ++mt)
                gac[j][mt] = __builtin_amdgcn_mfma_f32_16x16x32_bf16(
                    afr[mt], bf, gac[j][mt], 0, 0, 0);
        }
    }

    // ---- Epilogue: h_out = h + z*(tanh(g+bh) - h)
    #pragma unroll
    for (int j = 0; j < 2; ++j) {
        int col = 32 * wv + j * 16 + m0;
        #pragma unroll
        for (int mt = 0; mt < 2; ++mt) {
            #pragma unroll
            for (int rg = 0; rg < 4; ++rg) {
                int row = mt * 16 + q * 4 + rg;
                float zs = sigmoid_f(rz[2 + j][mt][rg] + bzv[j]);
                float gv = tanh_f(gac[j][mt][rg] + bhv[j]);
                float hval = rz[j][mt][rg];
                out[(size_t)(rowBase + row) * 256 + col] = hval + zs * (gv - hval);
            }
        }
    }
}

extern "C" void kernel_launch(void* const* d_in, const int* in_sizes, int n_in,
                              void* d_out, int out_size, void* d_ws, size_t ws_size,
                              hipStream_t stream) {
    const float* x   = (const float*)d_in[0];
    const float* h   = (const float*)d_in[1];
    const float* wr  = (const float*)d_in[2];
    const float* wz  = (const float*)d_in[3];
    const float* whh = (const float*)d_in[4];
    const float* whx = (const float*)d_in[5];
    const float* br  = (const float*)d_in[6];
    const float* bz  = (const float*)d_in[7];
    const float* bh  = (const float*)d_in[8];
    float* out = (float*)d_out;

    unsigned short* wrz = (unsigned short*)d_ws;       // 512 KB
    unsigned short* wg  = wrz + WRZ_ELEMS;             // 256 KB

    prep_weights<<<192, 256, 0, stream>>>(wr, wz, whh, whx, wrz, wg);
    gru_fused<<<B_TOT / MT, 512, 0, stream>>>(x, h, wrz, wg, br, bz, bh, out);
}